// Round 14
// baseline (366.889 us; speedup 1.0000x reference)
//
#include <hip/hip_runtime.h>
#include <hip/hip_bf16.h>

#define D_MODEL 1024
#define N_HEAD  16
#define D_K     64
#define FFN_DIM 4096
#define B_SZ    2
#define L_SEQ   2048
#define ROWS    (B_SZ * L_SEQ)   // 4096
#define PST     68               // Ps/Qs LDS row stride (shorts): proven 0-conflict (R9/R10)

typedef float  floatx4 __attribute__((ext_vector_type(4)));
typedef short  shortx8 __attribute__((ext_vector_type(8)));

__device__ __forceinline__ unsigned short f2bf(float f) {
    unsigned int u = __float_as_uint(f);
    unsigned int rounding = 0x7fffu + ((u >> 16) & 1u);
    return (unsigned short)((u + rounding) >> 16);
}
__device__ __forceinline__ float bf2f(unsigned short u) {
    return __uint_as_float(((unsigned int)u) << 16);
}

// async global->LDS 16B copy; LDS dest is wave-uniform base + lane*16
__device__ __forceinline__ void glds16(const unsigned short* g, unsigned short* l) {
    __builtin_amdgcn_global_load_lds(
        (const __attribute__((address_space(1))) unsigned int*)g,
        (__attribute__((address_space(3))) unsigned int*)l, 16, 0, 0);
}

// ---- T1: XCD-chunked blockIdx remap (R6, verified: attn FETCH 69.7->12.4 MB).
// Linear wg id round-robins the 8 XCDs (id%8 = XCD). Decode groups of 8 col-tiles x
// consecutive row-tiles so blocks sharing A-strips/B-panels co-reside per-XCD L2.
// Bijective when nwg%8==0 and gx%8==0 (all our grids).
__device__ __forceinline__ void xcd_remap_gemm(int& bx, int& by, int& bz) {
    const int gx = gridDim.x, gy = gridDim.y, gz = gridDim.z;
    const int o = blockIdx.x + gx * (blockIdx.y + gy * blockIdx.z);
    const int nwg = gx * gy * gz;
    const int t = (o & 7) * (nwg >> 3) + (o >> 3);
    const int zsz = gx * gy;
    bz = t / zsz;
    const int w = t - bz * zsz;
    const int grp = w / (8 * gy);
    const int in  = w - grp * (8 * gy);
    by = in >> 3;
    bx = grp * 8 + (in & 7);
}

// ---------- LayerNorm: one block per row of 1024, fp32 in -> bf16 out.
// R13: wave-shfl reduction (6 shfl_xor/wave + one 4-elem LDS combine + ONE barrier).
__global__ __launch_bounds__(256) void ln_kernel(const float* __restrict__ x,
                                                 const float* __restrict__ g,
                                                 const float* __restrict__ b,
                                                 unsigned short* __restrict__ out) {
    const int row = blockIdx.x;
    const int tid = threadIdx.x;
    const float* xr = x + (size_t)row * D_MODEL;
    float4 xv = *reinterpret_cast<const float4*>(&xr[tid * 4]);
    float v[4] = {xv.x, xv.y, xv.z, xv.w};
    float s  = (v[0] + v[1]) + (v[2] + v[3]);
    float ss = (v[0] * v[0] + v[1] * v[1]) + (v[2] * v[2] + v[3] * v[3]);
#pragma unroll
    for (int off = 1; off < 64; off <<= 1) {
        s  += __shfl_xor(s, off);
        ss += __shfl_xor(ss, off);
    }
    __shared__ float r1[4], r2[4];
    if ((tid & 63) == 0) { r1[tid >> 6] = s; r2[tid >> 6] = ss; }
    __syncthreads();
    const float ts  = (r1[0] + r1[1]) + (r1[2] + r1[3]);
    const float tss = (r2[0] + r2[1]) + (r2[2] + r2[3]);
    const float mean = ts * (1.0f / D_MODEL);
    const float var  = tss * (1.0f / D_MODEL) - mean * mean;
    const float inv  = rsqrtf(var + 1e-5f);
    unsigned short* orow = out + (size_t)row * D_MODEL;
    ushort4 o;
    o.x = f2bf((v[0] - mean) * inv * g[tid * 4 + 0] + b[tid * 4 + 0]);
    o.y = f2bf((v[1] - mean) * inv * g[tid * 4 + 1] + b[tid * 4 + 1]);
    o.z = f2bf((v[2] - mean) * inv * g[tid * 4 + 2] + b[tid * 4 + 2]);
    o.w = f2bf((v[3] - mean) * inv * g[tid * 4 + 3] + b[tid * 4 + 3]);
    *reinterpret_cast<ushort4*>(&orow[tid * 4]) = o;
}

// ---------- Transpose+cast: W fp32 [K][N] -> Wt bf16 [N][K] ----------
__global__ __launch_bounds__(256) void transpose_cast(const float* __restrict__ W,
                                                      unsigned short* __restrict__ Wt,
                                                      int K, int N) {
    __shared__ unsigned short T[32][33];
    const int t = threadIdx.x;
    const int k0 = blockIdx.y * 32, n0 = blockIdx.x * 32;
    const int kr = t >> 3, nc = (t & 7) * 4;
    float4 w = *reinterpret_cast<const float4*>(&W[(size_t)(k0 + kr) * N + n0 + nc]);
    T[kr][nc + 0] = f2bf(w.x); T[kr][nc + 1] = f2bf(w.y);
    T[kr][nc + 2] = f2bf(w.z); T[kr][nc + 3] = f2bf(w.w);
    __syncthreads();
    const int nr = t >> 3, kc = (t & 7) * 4;
    ushort4 o;
    o.x = T[kc + 0][nr]; o.y = T[kc + 1][nr];
    o.z = T[kc + 2][nr]; o.w = T[kc + 3][nr];
    *reinterpret_cast<ushort4*>(&Wt[(size_t)(n0 + nr) * K + k0 + kc]) = o;
}

// ---------- 4x square (1024x1024) transpose in one dispatch, z selects matrix ----------
__global__ __launch_bounds__(256) void transpose_cast4(const float* s0, const float* s1,
                                                       const float* s2, const float* s3,
                                                       unsigned short* d0, unsigned short* d1,
                                                       unsigned short* d2, unsigned short* d3) {
    const int z = blockIdx.z;
    const float* W = (z == 0) ? s0 : (z == 1) ? s1 : (z == 2) ? s2 : s3;
    unsigned short* Wt = (z == 0) ? d0 : (z == 1) ? d1 : (z == 2) ? d2 : d3;
    __shared__ unsigned short T[32][33];
    const int t = threadIdx.x;
    const int k0 = blockIdx.y * 32, n0 = blockIdx.x * 32;
    const int kr = t >> 3, nc = (t & 7) * 4;
    float4 w = *reinterpret_cast<const float4*>(&W[(size_t)(k0 + kr) * D_MODEL + n0 + nc]);
    T[kr][nc + 0] = f2bf(w.x); T[kr][nc + 1] = f2bf(w.y);
    T[kr][nc + 2] = f2bf(w.z); T[kr][nc + 3] = f2bf(w.w);
    __syncthreads();
    const int nr = t >> 3, kc = (t & 7) * 4;
    ushort4 o;
    o.x = T[kc + 0][nr]; o.y = T[kc + 1][nr];
    o.z = T[kc + 2][nr]; o.w = T[kc + 3][nr];
    *reinterpret_cast<ushort4*>(&Wt[(size_t)(n0 + nr) * D_MODEL + k0 + kc]) = o;
}

// ===== R9 GEMM: BK=32, 2-phase dbuf. Swizzle proven R0-R6.
// R14: mfma_gemm/splitk use SWAPPED mfma (bf, af) -> C^T fragments: thread holds 4
// CONSECUTIVE n for fixed m -> float4/ushort4 stores + float4 bias/res reads (64
// scalar stores -> 16 vector). Same trick verified in attn R10. QKV keeps original
// order (its V-output n-major layout benefits from the unswapped mapping).
// setprio NOT applied to GEMMs: m190 measured it harmful on lockstep GEMM.

#define GEMM_STAGE(AS, BS, KT)                                            \
    do {                                                                  \
        glds16(A  + sA0 + (KT), &AS[p0 * 8]);                             \
        glds16(A  + sA1 + (KT), &AS[p1 * 8]);                             \
        glds16(Wt + sB0 + (KT), &BS[p0 * 8]);                             \
        glds16(Wt + sB1 + (KT), &BS[p1 * 8]);                             \
    } while (0)

#define GEMM_COMPUTE(AS, BS)                                              \
    do {                                                                  \
        shortx8 af[4], bf[4];                                             \
        _Pragma("unroll")                                                 \
        for (int i = 0; i < 4; ++i)                                       \
            af[i] = *reinterpret_cast<const shortx8*>(&AS[offA[i]]);      \
        _Pragma("unroll")                                                 \
        for (int j = 0; j < 4; ++j)                                       \
            bf[j] = *reinterpret_cast<const shortx8*>(&BS[offB[j]]);      \
        _Pragma("unroll")                                                 \
        for (int i = 0; i < 4; ++i)                                       \
            _Pragma("unroll")                                             \
            for (int j = 0; j < 4; ++j)                                   \
                acc[i][j] = __builtin_amdgcn_mfma_f32_16x16x32_bf16(af[i], bf[j], acc[i][j], 0, 0, 0); \
    } while (0)

// swapped-operand variant: acc[i][j] holds C^T -> rows n (from bf), cols m (from af)
#define GEMM_COMPUTE_T(AS, BS)                                            \
    do {                                                                  \
        shortx8 af[4], bf[4];                                             \
        _Pragma("unroll")                                                 \
        for (int i = 0; i < 4; ++i)                                       \
            af[i] = *reinterpret_cast<const shortx8*>(&AS[offA[i]]);      \
        _Pragma("unroll")                                                 \
        for (int j = 0; j < 4; ++j)                                       \
            bf[j] = *reinterpret_cast<const shortx8*>(&BS[offB[j]]);      \
        _Pragma("unroll")                                                 \
        for (int i = 0; i < 4; ++i)                                       \
            _Pragma("unroll")                                             \
            for (int j = 0; j < 4; ++j)                                   \
                acc[i][j] = __builtin_amdgcn_mfma_f32_16x16x32_bf16(bf[j], af[i], acc[i][j], 0, 0, 0); \
    } while (0)

#define GEMM_PREAMBLE                                                     \
    const int tid  = threadIdx.x;                                         \
    const int lane = tid & 63;                                            \
    const int wave = tid >> 6;                                            \
    int bx, by, bz;                                                       \
    xcd_remap_gemm(bx, by, bz);                                           \
    const int row0 = by * 128, col0 = bx * 128;                           \
    const int wr = (wave >> 1) * 64, wc = (wave & 1) * 64;                \
    floatx4 acc[4][4] = {};                                               \
    const int p0 = tid,       r0s = p0 >> 2, k0s = (((p0 & 3) - (r0s >> 1)) & 3) * 8; \
    const int p1 = tid + 256, r1s = p1 >> 2, k1s = (((p1 & 3) - (r1s >> 1)) & 3) * 8; \
    const int am = (lane & 15);                                           \
    const size_t sA0 = (size_t)(row0 + r0s) * K + k0s;                    \
    const size_t sA1 = (size_t)(row0 + r1s) * K + k1s;                    \
    const size_t sB0 = (size_t)(col0 + r0s) * K + k0s;                    \
    const size_t sB1 = (size_t)(col0 + r1s) * K + k1s;                    \
    int offA[4], offB[4];                                                 \
    _Pragma("unroll")                                                     \
    for (int i = 0; i < 4; ++i) {                                         \
        const int Ra = wr + i * 16 + am;                                  \
        offA[i] = Ra * 32 + (((lane >> 4) + (Ra >> 1)) & 3) * 8;          \
        const int Rb = wc + i * 16 + am;                                  \
        offB[i] = Rb * 32 + (((lane >> 4) + (Rb >> 1)) & 3) * 8;          \
    }

// ---------- MFMA bf16 GEMM (2-phase dbuf, C^T epilogue). A [M][K]; Wt [N][K]. ----------
template <int SILU, int HAS_RES, int OUT_BF16>
__global__ __launch_bounds__(256) void mfma_gemm(const unsigned short* __restrict__ A,
                                                 const unsigned short* __restrict__ Wt,
                                                 const float* __restrict__ bias,
                                                 const float* __restrict__ res,
                                                 void* __restrict__ outP,
                                                 int M, int N, int K) {
    __shared__ unsigned short As0[128 * 32], As1[128 * 32];
    __shared__ unsigned short Bs0[128 * 32], Bs1[128 * 32];
    GEMM_PREAMBLE

    GEMM_STAGE(As0, Bs0, 0);
    __syncthreads();
    for (int kt = 0; kt < K; kt += 64) {
        GEMM_STAGE(As1, Bs1, kt + 32);
        GEMM_COMPUTE_T(As0, Bs0);
        __syncthreads();
        if (kt + 64 < K) GEMM_STAGE(As0, Bs0, kt + 64);
        GEMM_COMPUTE_T(As1, Bs1);
        __syncthreads();
    }

    const int cq = (lane >> 4) * 4;
    const int cn = lane & 15;
#pragma unroll
    for (int i = 0; i < 4; ++i) {
#pragma unroll
        for (int j = 0; j < 4; ++j) {
            const int m  = row0 + wr + i * 16 + cn;
            const int n0 = col0 + wc + j * 16 + cq;
            const float4 bb = *reinterpret_cast<const float4*>(&bias[n0]);
            float v[4] = {acc[i][j][0] + bb.x, acc[i][j][1] + bb.y,
                          acc[i][j][2] + bb.z, acc[i][j][3] + bb.w};
#pragma unroll
            for (int r = 0; r < 4; ++r)
                if (SILU) v[r] = v[r] / (1.0f + __expf(-v[r]));
            if (HAS_RES) {
                float4 rr = *reinterpret_cast<const float4*>(&res[(size_t)m * N + n0]);
                v[0] += rr.x; v[1] += rr.y; v[2] += rr.z; v[3] += rr.w;
            }
            if (OUT_BF16) {
                ushort4 o;
                o.x = f2bf(v[0]); o.y = f2bf(v[1]); o.z = f2bf(v[2]); o.w = f2bf(v[3]);
                *reinterpret_cast<ushort4*>(&((unsigned short*)outP)[(size_t)m * N + n0]) = o;
            } else {
                float4 o; o.x = v[0]; o.y = v[1]; o.z = v[2]; o.w = v[3];
                *reinterpret_cast<float4*>(&((float*)outP)[(size_t)m * N + n0]) = o;
            }
        }
    }
}

// ---------- Fused QKV GEMM: N=3072 over concatenated [3072][1024] weights ----------
__global__ __launch_bounds__(256) void mfma_gemm_qkv(const unsigned short* __restrict__ A,
                                                     const unsigned short* __restrict__ Wt,
                                                     const float* __restrict__ bq,
                                                     const float* __restrict__ bk,
                                                     const float* __restrict__ bv,
                                                     unsigned short* __restrict__ qb,
                                                     unsigned short* __restrict__ kb,
                                                     unsigned short* __restrict__ vtb) {
    const int K = D_MODEL, M = ROWS;
    __shared__ unsigned short As0[128 * 32], As1[128 * 32];
    __shared__ unsigned short Bs0[128 * 32], Bs1[128 * 32];
    GEMM_PREAMBLE

    GEMM_STAGE(As0, Bs0, 0);
    __syncthreads();
    for (int kt = 0; kt < K; kt += 64) {
        GEMM_STAGE(As1, Bs1, kt + 32);
        GEMM_COMPUTE(As0, Bs0);
        __syncthreads();
        if (kt + 64 < K) GEMM_STAGE(As0, Bs0, kt + 64);
        GEMM_COMPUTE(As1, Bs1);
        __syncthreads();
    }

    const int cq = (lane >> 4) * 4;
    const int cn = lane & 15;
    const int sel = col0 >> 10;                 // 0=Q 1=K 2=V (block-uniform)
    const int nbase = col0 & 1023;
    const float* bias = (sel == 0) ? bq : (sel == 1) ? bk : bv;
    // fold 1/sqrt(Dk) AND log2(e) into Q so attention uses a single v_exp_f32
    // (exact: softmax(S) == softmax-base-2(S*log2e)); 0.125 * 1.4426950408889634
    const float scl = (sel == 0) ? 0.18033688511157292f : 1.0f;
#pragma unroll
    for (int i = 0; i < 4; ++i) {
#pragma unroll
        for (int j = 0; j < 4; ++j) {
            const int n = nbase + wc + j * 16 + cn;
            const float bb = bias[n];
            if (sel == 2) {
                const int m0 = row0 + wr + i * 16 + cq;
                ushort4 o;
                o.x = f2bf(acc[i][j][0] + bb);
                o.y = f2bf(acc[i][j][1] + bb);
                o.z = f2bf(acc[i][j][2] + bb);
                o.w = f2bf(acc[i][j][3] + bb);
                *reinterpret_cast<ushort4*>(&vtb[(size_t)n * M + m0]) = o;
            } else {
                unsigned short* dst = (sel == 0) ? qb : kb;
#pragma unroll
                for (int r = 0; r < 4; ++r) {
                    const int m = row0 + wr + i * 16 + cq + r;
                    dst[(size_t)m * D_MODEL + n] = f2bf((acc[i][j][r] + bb) * scl);
                }
            }
        }
    }
}

// ---------- Split-K GEMM: z = K-slice; raw bf16 partials (C^T epilogue) ----------
__global__ __launch_bounds__(256) void mfma_gemm_splitk(const unsigned short* __restrict__ A,
                                                        const unsigned short* __restrict__ Wt,
                                                        unsigned short* __restrict__ parts,
                                                        int M, int N, int KS) {
    __shared__ unsigned short As0[128 * 32], As1[128 * 32];
    __shared__ unsigned short Bs0[128 * 32], Bs1[128 * 32];
    const int K = KS * gridDim.z;
    GEMM_PREAMBLE
    const int kbeg = bz * KS;
    unsigned short* outp = parts + (size_t)bz * M * N;

    GEMM_STAGE(As0, Bs0, kbeg);
    __syncthreads();
    for (int kt = kbeg; kt < kbeg + KS; kt += 64) {
        GEMM_STAGE(As1, Bs1, kt + 32);
        GEMM_COMPUTE_T(As0, Bs0);
        __syncthreads();
        if (kt + 64 < kbeg + KS) GEMM_STAGE(As0, Bs0, kt + 64);
        GEMM_COMPUTE_T(As1, Bs1);
        __syncthreads();
    }

    const int cq = (lane >> 4) * 4;
    const int cn = lane & 15;
#pragma unroll
    for (int i = 0; i < 4; ++i)
#pragma unroll
        for (int j = 0; j < 4; ++j) {
            const int m  = row0 + wr + i * 16 + cn;
            const int n0 = col0 + wc + j * 16 + cq;
            ushort4 o;
            o.x = f2bf(acc[i][j][0]); o.y = f2bf(acc[i][j][1]);
            o.z = f2bf(acc[i][j][2]); o.w = f2bf(acc[i][j][3]);
            *reinterpret_cast<ushort4*>(&outp[(size_t)m * N + n0]) = o;
        }
}

// ---------- combine: out = p0 + p1 + bias + res ----------
__global__ __launch_bounds__(256) void combine_kernel(const unsigned short* __restrict__ p0,
                                                      const unsigned short* __restrict__ p1,
                                                      const float* __restrict__ bias,
                                                      const float* __restrict__ res,
                                                      float* __restrict__ out) {
    const size_t e0 = ((size_t)blockIdx.x * 256 + threadIdx.x) * 4;
    const int col = (int)(e0 & 1023);
    ushort4 a = *reinterpret_cast<const ushort4*>(&p0[e0]);
    ushort4 b = *reinterpret_cast<const ushort4*>(&p1[e0]);
    float4 r = *reinterpret_cast<const float4*>(&res[e0]);
    float4 o;
    o.x = bf2f(a.x) + bf2f(b.x) + bias[col + 0] + r.x;
    o.y = bf2f(a.y) + bf2f(b.y) + bias[col + 1] + r.y;
    o.z = bf2f(a.z) + bf2f(b.z) + bias[col + 2] + r.z;
    o.w = bf2f(a.w) + bf2f(b.w) + bias[col + 3] + r.w;
    *reinterpret_cast<float4*>(&out[e0]) = o;
}

// ---------- MFMA attention: R13 config (session best, 58.7 us) — UNCHANGED.
// R10 structure + T5 setprio around MFMA clusters (confirmed small positive).
__global__ __launch_bounds__(512) void attn_mfma(const unsigned short* __restrict__ Q,
                                                 const unsigned short* __restrict__ K,
                                                 const unsigned short* __restrict__ Vt,
                                                 const int* __restrict__ mask,
                                                 unsigned short* __restrict__ att) {
    const int tid  = threadIdx.x;
    const int lane = tid & 63;
    const int wave = tid >> 6;          // 0..7
    // plain chunked XCD remap (row-major decode: q-tile fastest -> chunk shares K/V)
    const int o = blockIdx.x + gridDim.x * (blockIdx.y + gridDim.y * blockIdx.z);
    const int nwg = gridDim.x * gridDim.y * gridDim.z;
    const int t = (o & 7) * (nwg >> 3) + (o >> 3);
    const int qx = t % gridDim.x;
    const int h  = (t / gridDim.x) % gridDim.y;
    const int b  = t / (gridDim.x * gridDim.y);
    const int q0 = qx * 128;

    __shared__ unsigned short Qs[128 * PST];
    __shared__ unsigned short Ks[2][64 * 64];
    __shared__ unsigned short Vs[2][64 * 64];
    __shared__ unsigned short Ps[128 * PST];
    __shared__ unsigned char mkb[128];

    const int am = lane & 15;
    const int aq = (lane >> 4) * 8;
    const int cq = (lane >> 4) * 4;
    const int cn = lane & 15;

    // stage Q tile (once, via VGPR; padded layout): 128 rows x 8 chunks = 1024 chunks
    for (int c = tid; c < 1024; c += 512) {
        const int r = c >> 3, off = (c & 7) * 8;
        *reinterpret_cast<uint4*>(&Qs[r * PST + off]) =
            *reinterpret_cast<const uint4*>(&Q[(size_t)(b * L_SEQ + q0 + r) * D_MODEL + h * D_K + off]);
    }

    // swizzled staging: LDS chunk p holds (row=p>>3, c8=((p&7)-row)&7); 512 chunks
    // per sub-tile, one per thread per sub-tile for each of Ks and Vs.
    const int p0 = tid, sr0 = p0 >> 3, sc0 = (((p0 & 7) - sr0) & 7) * 8;
    const unsigned short* K0 = K + (size_t)(b * L_SEQ + sr0) * D_MODEL + h * D_K + sc0;
    const unsigned short* V0 = Vt + (size_t)(h * D_K + sr0) * ROWS + b * L_SEQ + sc0;

    // fragment read offsets (loop-invariant): row R = t*16+am, chunk c8 = kt*4 + (lane>>4)
    int offF[2][4];
#pragma unroll
    for (int kt = 0; kt < 2; ++kt)
#pragma unroll
        for (int tt = 0; tt < 4; ++tt) {
            const int R = tt * 16 + am;
            offF[kt][tt] = R * 64 + (((kt * 4 + (lane >> 4)) + R) & 7) * 8;
        }

    __syncthreads();

    shortx8 aQ[2];
    aQ[0] = *reinterpret_cast<const shortx8*>(&Qs[(wave * 16 + am) * PST + aq]);
    aQ[1] = *reinterpret_cast<const shortx8*>(&Qs[(wave * 16 + am) * PST + 32 + aq]);

    floatx4 oacc[4] = {};
    float lsum = 0.0f;

    for (int j0 = 0; j0 < L_SEQ; j0 += 128) {
        __syncthreads();
        glds16(K0 + (size_t)j0 * D_MODEL,        &Ks[0][p0 * 8]);
        glds16(K0 + (size_t)(j0 + 64) * D_MODEL, &Ks[1][p0 * 8]);
        glds16(V0 + j0,      &Vs[0][p0 * 8]);
        glds16(V0 + j0 + 64, &Vs[1][p0 * 8]);
        if (tid < 128) mkb[tid] = (unsigned char)(mask[b * L_SEQ + j0 + tid] != 0);
        __syncthreads();

#pragma unroll
        for (int u = 0; u < 2; ++u) {
            // S^T = K x Q^T: sacc[jt][r] = S[k = u*64 + 16jt + cq + r][q = wave*16 + cn]
            floatx4 sacc[4] = {};
            __builtin_amdgcn_s_setprio(1);
#pragma unroll
            for (int kt = 0; kt < 2; ++kt)
#pragma unroll
                for (int jt = 0; jt < 4; ++jt) {
                    shortx8 bK = *reinterpret_cast<const shortx8*>(&Ks[u][offF[kt][jt]]);
                    sacc[jt] = __builtin_amdgcn_mfma_f32_16x16x32_bf16(bK, aQ[kt], sacc[jt], 0, 0, 0);
                }
            __builtin_amdgcn_s_setprio(0);
            // P = exp2(S^T) masked; pack k-pairs via v_cvt_pk_bf16_f32 -> ds_write_b64
            // into Ps[q][k] (same layout the PV reads expect).
#pragma unroll
            for (int jt = 0; jt < 4; ++jt) {
                uchar4 mb = *reinterpret_cast<const uchar4*>(&mkb[u * 64 + jt * 16 + cq]);
                float pv0 = mb.x ? __builtin_amdgcn_exp2f(sacc[jt][0]) : 0.0f;
                float pv1 = mb.y ? __builtin_amdgcn_exp2f(sacc[jt][1]) : 0.0f;
                float pv2 = mb.z ? __builtin_amdgcn_exp2f(sacc[jt][2]) : 0.0f;
                float pv3 = mb.w ? __builtin_amdgcn_exp2f(sacc[jt][3]) : 0.0f;
                lsum += (pv0 + pv1) + (pv2 + pv3);
                unsigned int pk0, pk1;
                asm("v_cvt_pk_bf16_f32 %0, %1, %2" : "=v"(pk0) : "v"(pv0), "v"(pv1));
                asm("v_cvt_pk_bf16_f32 %0, %1, %2" : "=v"(pk1) : "v"(pv2), "v"(pv3));
                uint2 w; w.x = pk0; w.y = pk1;
                *reinterpret_cast<uint2*>(&Ps[(wave * 16 + cn) * PST + jt * 16 + cq]) = w;
            }
            // O += P x V (wave-private Ps rows; DS in-order within wave -> safe reuse)
            __builtin_amdgcn_s_setprio(1);
#pragma unroll
            for (int kt = 0; kt < 2; ++kt) {
                shortx8 aP = *reinterpret_cast<const shortx8*>(&Ps[(wave * 16 + am) * PST + kt * 32 + aq]);
#pragma unroll
                for (int dt = 0; dt < 4; ++dt) {
                    shortx8 bV = *reinterpret_cast<const shortx8*>(&Vs[u][offF[kt][dt]]);
                    oacc[dt] = __builtin_amdgcn_mfma_f32_16x16x32_bf16(aP, bV, oacc[dt], 0, 0, 0);
                }
            }
            __builtin_amdgcn_s_setprio(0);
        }
    }

    // lsum: thread holds partial for q = wave*16+cn over its k; reduce across the
    // 4 lanes sharing cn (bits 4,5), then redistribute to the oacc layout (q=cq+r).
    float lt = lsum;
    lt += __shfl_xor(lt, 16);
    lt += __shfl_xor(lt, 32);
    float linv[4];
#pragma unroll
    for (int r = 0; r < 4; ++r)
        linv[r] = 1.0f / __shfl(lt, cq + r);

#pragma unroll
    for (int dt = 0; dt < 4; ++dt)
#pragma unroll
        for (int r = 0; r < 4; ++r) {
            att[(size_t)(b * L_SEQ + q0 + wave * 16 + cq + r) * D_MODEL + h * D_K + dt * 16 + cn] =
                f2bf(oacc[dt][r] * linv[r]);
        }
}

extern "C" void kernel_launch(void* const* d_in, const int* in_sizes, int n_in,
                              void* d_out, int out_size, void* d_ws, size_t ws_size,
                              hipStream_t stream) {
    const float* x     = (const float*)d_in[0];
    const int*   mask  = (const int*)d_in[1];
    const float* ln1_g = (const float*)d_in[2];
    const float* ln1_b = (const float*)d_in[3];
    const float* Wq    = (const float*)d_in[4];
    const float* bq    = (const float*)d_in[5];
    const float* Wk    = (const float*)d_in[6];
    const float* bk    = (const float*)d_in[7];
    const float* Wv    = (const float*)d_in[8];
    const float* bv    = (const float*)d_in[9];
    const float* Wo    = (const float*)d_in[10];
    const float* bo    = (const float*)d_in[11];
    const float* ln2_g = (const float*)d_in[12];
    const float* ln2_b = (const float*)d_in[13];
    const float* W1    = (const float*)d_in[14];
    const float* b1    = (const float*)d_in[15];
    const float* W2    = (const float*)d_in[16];
    const float* b2    = (const float*)d_in[17];
    float* out = (float*)d_out;

    float* ws = (float*)d_ws;
    const size_t SZ = (size_t)ROWS * D_MODEL;  // 4M elements; fp32 slot = 16 MB

    unsigned short* nx  = (unsigned short*)(ws + 0 * SZ);   // 0-8 MB: LN1/LN2 out bf16
    unsigned short* qb  = (unsigned short*)(ws + 1 * SZ);   // 16-24: Q bf16 (pre-scaled)
    unsigned short* kb  = qb + SZ;                          // 24-32: K bf16
    unsigned short* vtb = (unsigned short*)(ws + 2 * SZ);   // 32-40: V^T bf16
    unsigned short* attb = vtb + SZ;                        // 40-48: att bf16
    float* x1  = out;                                       // residual stream in d_out
    unsigned short* nx2 = nx;                               // slot0 reuse
    unsigned short* h = (unsigned short*)(ws + 2 * SZ);     // 32-64: FFN hidden bf16
    unsigned short* parts = (unsigned short*)(ws + 0 * SZ); // 0-16: FFN2 split-K partials

    unsigned short* WqkvT = (unsigned short*)(ws + 4 * SZ); // 64-70: concat [3072][1024]
    unsigned short* WqT = WqkvT;
    unsigned short* WkT = WqkvT + (size_t)D_MODEL * D_MODEL;
    unsigned short* WvT = WkT + (size_t)D_MODEL * D_MODEL;
    unsigned short* WoT = WvT + (size_t)D_MODEL * D_MODEL;  // 70-72
    unsigned short* W1T = (unsigned short*)(ws + 1 * SZ);   // 16-24 (qb/kb dead after attn)
    unsigned short* W2T = W1T + (size_t)D_MODEL * FFN_DIM;  // 24-32

    ln_kernel<<<ROWS, 256, 0, stream>>>(x, ln1_g, ln1_b, nx);

    transpose_cast4<<<dim3(32, 32, 4), 256, 0, stream>>>(Wq, Wk, Wv, Wo, WqT, WkT, WvT, WoT);

    mfma_gemm_qkv<<<dim3(3072 / 128, ROWS / 128), 256, 0, stream>>>(
        nx, WqkvT, bq, bk, bv, qb, kb, vtb);

    attn_mfma<<<dim3(L_SEQ / 128, N_HEAD, B_SZ), 512, 0, stream>>>(qb, kb, vtb, mask, attb);

    transpose_cast<<<dim3(FFN_DIM / 32, D_MODEL / 32), 256, 0, stream>>>(W1, W1T, D_MODEL, FFN_DIM);
    transpose_cast<<<dim3(D_MODEL / 32, FFN_DIM / 32), 256, 0, stream>>>(W2, W2T, FFN_DIM, D_MODEL);

    mfma_gemm<0, 1, 0><<<dim3(D_MODEL / 128, ROWS / 128), 256, 0, stream>>>(
        attb, WoT, bo, x, x1, ROWS, D_MODEL, D_MODEL);

    ln_kernel<<<ROWS, 256, 0, stream>>>(x1, ln2_g, ln2_b, nx2);

    mfma_gemm<1, 0, 1><<<dim3(FFN_DIM / 128, ROWS / 128), 256, 0, stream>>>(
        nx2, W1T, b1, nullptr, h, ROWS, FFN_DIM, D_MODEL);

    mfma_gemm_splitk<<<dim3(D_MODEL / 128, ROWS / 128, 2), 256, 0, stream>>>(
        h, W2T, parts, ROWS, D_MODEL, FFN_DIM / 2);
    combine_kernel<<<(ROWS * D_MODEL) / 1024, 256, 0, stream>>>(
        parts, parts + SZ, b2, x1, out);
}

// Round 15
// 357.052 us; speedup vs baseline: 1.0276x; 1.0276x over previous
//
#include <hip/hip_runtime.h>
#include <hip/hip_bf16.h>

#define D_MODEL 1024
#define N_HEAD  16
#define D_K     64
#define FFN_DIM 4096
#define B_SZ    2
#define L_SEQ   2048
#define ROWS    (B_SZ * L_SEQ)   // 4096
#define PST     68               // Ps/Qs LDS row stride (shorts): proven 0-conflict (R9/R10)

typedef float  floatx4 __attribute__((ext_vector_type(4)));
typedef short  shortx8 __attribute__((ext_vector_type(8)));

__device__ __forceinline__ unsigned short f2bf(float f) {
    unsigned int u = __float_as_uint(f);
    unsigned int rounding = 0x7fffu + ((u >> 16) & 1u);
    return (unsigned short)((u + rounding) >> 16);
}
__device__ __forceinline__ float bf2f(unsigned short u) {
    return __uint_as_float(((unsigned int)u) << 16);
}

// async global->LDS 16B copy; LDS dest is wave-uniform base + lane*16
__device__ __forceinline__ void glds16(const unsigned short* g, unsigned short* l) {
    __builtin_amdgcn_global_load_lds(
        (const __attribute__((address_space(1))) unsigned int*)g,
        (__attribute__((address_space(3))) unsigned int*)l, 16, 0, 0);
}

// ---- T1: XCD-chunked blockIdx remap (R6, verified: attn FETCH 69.7->12.4 MB).
// Linear wg id round-robins the 8 XCDs (id%8 = XCD). Decode groups of 8 col-tiles x
// consecutive row-tiles so blocks sharing A-strips/B-panels co-reside per-XCD L2.
// Bijective when nwg%8==0 and gx%8==0 (all our grids).
__device__ __forceinline__ void xcd_remap_gemm(int& bx, int& by, int& bz) {
    const int gx = gridDim.x, gy = gridDim.y, gz = gridDim.z;
    const int o = blockIdx.x + gx * (blockIdx.y + gy * blockIdx.z);
    const int nwg = gx * gy * gz;
    const int t = (o & 7) * (nwg >> 3) + (o >> 3);
    const int zsz = gx * gy;
    bz = t / zsz;
    const int w = t - bz * zsz;
    const int grp = w / (8 * gy);
    const int in  = w - grp * (8 * gy);
    by = in >> 3;
    bx = grp * 8 + (in & 7);
}

// ---------- LayerNorm: one block per row of 1024, fp32 in -> bf16 out.
// R13: wave-shfl reduction (6 shfl_xor/wave + one 4-elem LDS combine + ONE barrier).
__global__ __launch_bounds__(256) void ln_kernel(const float* __restrict__ x,
                                                 const float* __restrict__ g,
                                                 const float* __restrict__ b,
                                                 unsigned short* __restrict__ out) {
    const int row = blockIdx.x;
    const int tid = threadIdx.x;
    const float* xr = x + (size_t)row * D_MODEL;
    float4 xv = *reinterpret_cast<const float4*>(&xr[tid * 4]);
    float v[4] = {xv.x, xv.y, xv.z, xv.w};
    float s  = (v[0] + v[1]) + (v[2] + v[3]);
    float ss = (v[0] * v[0] + v[1] * v[1]) + (v[2] * v[2] + v[3] * v[3]);
#pragma unroll
    for (int off = 1; off < 64; off <<= 1) {
        s  += __shfl_xor(s, off);
        ss += __shfl_xor(ss, off);
    }
    __shared__ float r1[4], r2[4];
    if ((tid & 63) == 0) { r1[tid >> 6] = s; r2[tid >> 6] = ss; }
    __syncthreads();
    const float ts  = (r1[0] + r1[1]) + (r1[2] + r1[3]);
    const float tss = (r2[0] + r2[1]) + (r2[2] + r2[3]);
    const float mean = ts * (1.0f / D_MODEL);
    const float var  = tss * (1.0f / D_MODEL) - mean * mean;
    const float inv  = rsqrtf(var + 1e-5f);
    unsigned short* orow = out + (size_t)row * D_MODEL;
    ushort4 o;
    o.x = f2bf((v[0] - mean) * inv * g[tid * 4 + 0] + b[tid * 4 + 0]);
    o.y = f2bf((v[1] - mean) * inv * g[tid * 4 + 1] + b[tid * 4 + 1]);
    o.z = f2bf((v[2] - mean) * inv * g[tid * 4 + 2] + b[tid * 4 + 2]);
    o.w = f2bf((v[3] - mean) * inv * g[tid * 4 + 3] + b[tid * 4 + 3]);
    *reinterpret_cast<ushort4*>(&orow[tid * 4]) = o;
}

// ---------- Transpose+cast: W fp32 [K][N] -> Wt bf16 [N][K] ----------
__global__ __launch_bounds__(256) void transpose_cast(const float* __restrict__ W,
                                                      unsigned short* __restrict__ Wt,
                                                      int K, int N) {
    __shared__ unsigned short T[32][33];
    const int t = threadIdx.x;
    const int k0 = blockIdx.y * 32, n0 = blockIdx.x * 32;
    const int kr = t >> 3, nc = (t & 7) * 4;
    float4 w = *reinterpret_cast<const float4*>(&W[(size_t)(k0 + kr) * N + n0 + nc]);
    T[kr][nc + 0] = f2bf(w.x); T[kr][nc + 1] = f2bf(w.y);
    T[kr][nc + 2] = f2bf(w.z); T[kr][nc + 3] = f2bf(w.w);
    __syncthreads();
    const int nr = t >> 3, kc = (t & 7) * 4;
    ushort4 o;
    o.x = T[kc + 0][nr]; o.y = T[kc + 1][nr];
    o.z = T[kc + 2][nr]; o.w = T[kc + 3][nr];
    *reinterpret_cast<ushort4*>(&Wt[(size_t)(n0 + nr) * K + k0 + kc]) = o;
}

// ---------- 4x square (1024x1024) transpose in one dispatch, z selects matrix ----------
__global__ __launch_bounds__(256) void transpose_cast4(const float* s0, const float* s1,
                                                       const float* s2, const float* s3,
                                                       unsigned short* d0, unsigned short* d1,
                                                       unsigned short* d2, unsigned short* d3) {
    const int z = blockIdx.z;
    const float* W = (z == 0) ? s0 : (z == 1) ? s1 : (z == 2) ? s2 : s3;
    unsigned short* Wt = (z == 0) ? d0 : (z == 1) ? d1 : (z == 2) ? d2 : d3;
    __shared__ unsigned short T[32][33];
    const int t = threadIdx.x;
    const int k0 = blockIdx.y * 32, n0 = blockIdx.x * 32;
    const int kr = t >> 3, nc = (t & 7) * 4;
    float4 w = *reinterpret_cast<const float4*>(&W[(size_t)(k0 + kr) * D_MODEL + n0 + nc]);
    T[kr][nc + 0] = f2bf(w.x); T[kr][nc + 1] = f2bf(w.y);
    T[kr][nc + 2] = f2bf(w.z); T[kr][nc + 3] = f2bf(w.w);
    __syncthreads();
    const int nr = t >> 3, kc = (t & 7) * 4;
    ushort4 o;
    o.x = T[kc + 0][nr]; o.y = T[kc + 1][nr];
    o.z = T[kc + 2][nr]; o.w = T[kc + 3][nr];
    *reinterpret_cast<ushort4*>(&Wt[(size_t)(n0 + nr) * D_MODEL + k0 + kc]) = o;
}

// ===== R9 GEMM: BK=32, 2-phase dbuf. Swizzle proven R0-R6.
// R15: reverted R14's C^T epilogue — per-thread 16B stores broke WAVE-level
// coalescing (16 lanes hit 16 different rows/cache-lines vs 16 consecutive n in
// one line before). Original scalar-but-coalesced epilogue restored.
// setprio NOT applied to GEMMs: m190 measured it harmful on lockstep GEMM.

#define GEMM_STAGE(AS, BS, KT)                                            \
    do {                                                                  \
        glds16(A  + sA0 + (KT), &AS[p0 * 8]);                             \
        glds16(A  + sA1 + (KT), &AS[p1 * 8]);                             \
        glds16(Wt + sB0 + (KT), &BS[p0 * 8]);                             \
        glds16(Wt + sB1 + (KT), &BS[p1 * 8]);                             \
    } while (0)

#define GEMM_COMPUTE(AS, BS)                                              \
    do {                                                                  \
        shortx8 af[4], bf[4];                                             \
        _Pragma("unroll")                                                 \
        for (int i = 0; i < 4; ++i)                                       \
            af[i] = *reinterpret_cast<const shortx8*>(&AS[offA[i]]);      \
        _Pragma("unroll")                                                 \
        for (int j = 0; j < 4; ++j)                                       \
            bf[j] = *reinterpret_cast<const shortx8*>(&BS[offB[j]]);      \
        _Pragma("unroll")                                                 \
        for (int i = 0; i < 4; ++i)                                       \
            _Pragma("unroll")                                             \
            for (int j = 0; j < 4; ++j)                                   \
                acc[i][j] = __builtin_amdgcn_mfma_f32_16x16x32_bf16(af[i], bf[j], acc[i][j], 0, 0, 0); \
    } while (0)

#define GEMM_PREAMBLE                                                     \
    const int tid  = threadIdx.x;                                         \
    const int lane = tid & 63;                                            \
    const int wave = tid >> 6;                                            \
    int bx, by, bz;                                                       \
    xcd_remap_gemm(bx, by, bz);                                           \
    const int row0 = by * 128, col0 = bx * 128;                           \
    const int wr = (wave >> 1) * 64, wc = (wave & 1) * 64;                \
    floatx4 acc[4][4] = {};                                               \
    const int p0 = tid,       r0s = p0 >> 2, k0s = (((p0 & 3) - (r0s >> 1)) & 3) * 8; \
    const int p1 = tid + 256, r1s = p1 >> 2, k1s = (((p1 & 3) - (r1s >> 1)) & 3) * 8; \
    const int am = (lane & 15);                                           \
    const size_t sA0 = (size_t)(row0 + r0s) * K + k0s;                    \
    const size_t sA1 = (size_t)(row0 + r1s) * K + k1s;                    \
    const size_t sB0 = (size_t)(col0 + r0s) * K + k0s;                    \
    const size_t sB1 = (size_t)(col0 + r1s) * K + k1s;                    \
    int offA[4], offB[4];                                                 \
    _Pragma("unroll")                                                     \
    for (int i = 0; i < 4; ++i) {                                         \
        const int Ra = wr + i * 16 + am;                                  \
        offA[i] = Ra * 32 + (((lane >> 4) + (Ra >> 1)) & 3) * 8;          \
        const int Rb = wc + i * 16 + am;                                  \
        offB[i] = Rb * 32 + (((lane >> 4) + (Rb >> 1)) & 3) * 8;          \
    }

// ---------- MFMA bf16 GEMM (2-phase dbuf). A [M][K]; Wt [N][K]. 128x128. ----------
template <int SILU, int HAS_RES, int OUT_BF16>
__global__ __launch_bounds__(256) void mfma_gemm(const unsigned short* __restrict__ A,
                                                 const unsigned short* __restrict__ Wt,
                                                 const float* __restrict__ bias,
                                                 const float* __restrict__ res,
                                                 void* __restrict__ outP,
                                                 int M, int N, int K) {
    __shared__ unsigned short As0[128 * 32], As1[128 * 32];
    __shared__ unsigned short Bs0[128 * 32], Bs1[128 * 32];
    GEMM_PREAMBLE

    GEMM_STAGE(As0, Bs0, 0);
    __syncthreads();
    for (int kt = 0; kt < K; kt += 64) {
        GEMM_STAGE(As1, Bs1, kt + 32);
        GEMM_COMPUTE(As0, Bs0);
        __syncthreads();
        if (kt + 64 < K) GEMM_STAGE(As0, Bs0, kt + 64);
        GEMM_COMPUTE(As1, Bs1);
        __syncthreads();
    }

    const int cq = (lane >> 4) * 4;
    const int cn = lane & 15;
#pragma unroll
    for (int i = 0; i < 4; ++i) {
#pragma unroll
        for (int j = 0; j < 4; ++j) {
            const int n = col0 + wc + j * 16 + cn;
            const float bb = bias[n];
#pragma unroll
            for (int r = 0; r < 4; ++r) {
                const int m = row0 + wr + i * 16 + cq + r;
                float v = acc[i][j][r] + bb;
                if (SILU) v = v / (1.0f + __expf(-v));
                if (HAS_RES) v += res[(size_t)m * N + n];
                if (OUT_BF16) ((unsigned short*)outP)[(size_t)m * N + n] = f2bf(v);
                else          ((float*)outP)[(size_t)m * N + n] = v;
            }
        }
    }
}

// ---------- Fused QKV GEMM: N=3072 over concatenated [3072][1024] weights ----------
__global__ __launch_bounds__(256) void mfma_gemm_qkv(const unsigned short* __restrict__ A,
                                                     const unsigned short* __restrict__ Wt,
                                                     const float* __restrict__ bq,
                                                     const float* __restrict__ bk,
                                                     const float* __restrict__ bv,
                                                     unsigned short* __restrict__ qb,
                                                     unsigned short* __restrict__ kb,
                                                     unsigned short* __restrict__ vtb) {
    const int K = D_MODEL, M = ROWS;
    __shared__ unsigned short As0[128 * 32], As1[128 * 32];
    __shared__ unsigned short Bs0[128 * 32], Bs1[128 * 32];
    GEMM_PREAMBLE

    GEMM_STAGE(As0, Bs0, 0);
    __syncthreads();
    for (int kt = 0; kt < K; kt += 64) {
        GEMM_STAGE(As1, Bs1, kt + 32);
        GEMM_COMPUTE(As0, Bs0);
        __syncthreads();
        if (kt + 64 < K) GEMM_STAGE(As0, Bs0, kt + 64);
        GEMM_COMPUTE(As1, Bs1);
        __syncthreads();
    }

    const int cq = (lane >> 4) * 4;
    const int cn = lane & 15;
    const int sel = col0 >> 10;                 // 0=Q 1=K 2=V (block-uniform)
    const int nbase = col0 & 1023;
    const float* bias = (sel == 0) ? bq : (sel == 1) ? bk : bv;
    // fold 1/sqrt(Dk) AND log2(e) into Q so attention uses a single v_exp_f32
    // (exact: softmax(S) == softmax-base-2(S*log2e)); 0.125 * 1.4426950408889634
    const float scl = (sel == 0) ? 0.18033688511157292f : 1.0f;
#pragma unroll
    for (int i = 0; i < 4; ++i) {
#pragma unroll
        for (int j = 0; j < 4; ++j) {
            const int n = nbase + wc + j * 16 + cn;
            const float bb = bias[n];
            if (sel == 2) {
                const int m0 = row0 + wr + i * 16 + cq;
                ushort4 o;
                o.x = f2bf(acc[i][j][0] + bb);
                o.y = f2bf(acc[i][j][1] + bb);
                o.z = f2bf(acc[i][j][2] + bb);
                o.w = f2bf(acc[i][j][3] + bb);
                *reinterpret_cast<ushort4*>(&vtb[(size_t)n * M + m0]) = o;
            } else {
                unsigned short* dst = (sel == 0) ? qb : kb;
#pragma unroll
                for (int r = 0; r < 4; ++r) {
                    const int m = row0 + wr + i * 16 + cq + r;
                    dst[(size_t)m * D_MODEL + n] = f2bf((acc[i][j][r] + bb) * scl);
                }
            }
        }
    }
}

// ---------- Split-K GEMM: z = K-slice; raw bf16 partials ----------
__global__ __launch_bounds__(256) void mfma_gemm_splitk(const unsigned short* __restrict__ A,
                                                        const unsigned short* __restrict__ Wt,
                                                        unsigned short* __restrict__ parts,
                                                        int M, int N, int KS) {
    __shared__ unsigned short As0[128 * 32], As1[128 * 32];
    __shared__ unsigned short Bs0[128 * 32], Bs1[128 * 32];
    const int K = KS * gridDim.z;
    GEMM_PREAMBLE
    const int kbeg = bz * KS;
    unsigned short* outp = parts + (size_t)bz * M * N;

    GEMM_STAGE(As0, Bs0, kbeg);
    __syncthreads();
    for (int kt = kbeg; kt < kbeg + KS; kt += 64) {
        GEMM_STAGE(As1, Bs1, kt + 32);
        GEMM_COMPUTE(As0, Bs0);
        __syncthreads();
        if (kt + 64 < kbeg + KS) GEMM_STAGE(As0, Bs0, kt + 64);
        GEMM_COMPUTE(As1, Bs1);
        __syncthreads();
    }

    const int cq = (lane >> 4) * 4;
    const int cn = lane & 15;
#pragma unroll
    for (int i = 0; i < 4; ++i)
#pragma unroll
        for (int j = 0; j < 4; ++j) {
            const int n = col0 + wc + j * 16 + cn;
#pragma unroll
            for (int r = 0; r < 4; ++r) {
                const int m = row0 + wr + i * 16 + cq + r;
                outp[(size_t)m * N + n] = f2bf(acc[i][j][r]);
            }
        }
}

// ---------- combine: out = p0 + p1 + bias + res ----------
__global__ __launch_bounds__(256) void combine_kernel(const unsigned short* __restrict__ p0,
                                                      const unsigned short* __restrict__ p1,
                                                      const float* __restrict__ bias,
                                                      const float* __restrict__ res,
                                                      float* __restrict__ out) {
    const size_t e0 = ((size_t)blockIdx.x * 256 + threadIdx.x) * 4;
    const int col = (int)(e0 & 1023);
    ushort4 a = *reinterpret_cast<const ushort4*>(&p0[e0]);
    ushort4 b = *reinterpret_cast<const ushort4*>(&p1[e0]);
    float4 r = *reinterpret_cast<const float4*>(&res[e0]);
    float4 o;
    o.x = bf2f(a.x) + bf2f(b.x) + bias[col + 0] + r.x;
    o.y = bf2f(a.y) + bf2f(b.y) + bias[col + 1] + r.y;
    o.z = bf2f(a.z) + bf2f(b.z) + bias[col + 2] + r.z;
    o.w = bf2f(a.w) + bf2f(b.w) + bias[col + 3] + r.w;
    *reinterpret_cast<float4*>(&out[e0]) = o;
}

// ---------- MFMA attention: R13 config (session best) — UNCHANGED.
// R10 structure (QBLK=128, 8 waves, dual 64-row K/V sub-tiles, swapped QK^T,
// packed cvt_pk Ps writes, single v_exp_f32) + T5 setprio around MFMA clusters.
__global__ __launch_bounds__(512) void attn_mfma(const unsigned short* __restrict__ Q,
                                                 const unsigned short* __restrict__ K,
                                                 const unsigned short* __restrict__ Vt,
                                                 const int* __restrict__ mask,
                                                 unsigned short* __restrict__ att) {
    const int tid  = threadIdx.x;
    const int lane = tid & 63;
    const int wave = tid >> 6;          // 0..7
    // plain chunked XCD remap (row-major decode: q-tile fastest -> chunk shares K/V)
    const int o = blockIdx.x + gridDim.x * (blockIdx.y + gridDim.y * blockIdx.z);
    const int nwg = gridDim.x * gridDim.y * gridDim.z;
    const int t = (o & 7) * (nwg >> 3) + (o >> 3);
    const int qx = t % gridDim.x;
    const int h  = (t / gridDim.x) % gridDim.y;
    const int b  = t / (gridDim.x * gridDim.y);
    const int q0 = qx * 128;

    __shared__ unsigned short Qs[128 * PST];
    __shared__ unsigned short Ks[2][64 * 64];
    __shared__ unsigned short Vs[2][64 * 64];
    __shared__ unsigned short Ps[128 * PST];
    __shared__ unsigned char mkb[128];

    const int am = lane & 15;
    const int aq = (lane >> 4) * 8;
    const int cq = (lane >> 4) * 4;
    const int cn = lane & 15;

    // stage Q tile (once, via VGPR; padded layout): 128 rows x 8 chunks = 1024 chunks
    for (int c = tid; c < 1024; c += 512) {
        const int r = c >> 3, off = (c & 7) * 8;
        *reinterpret_cast<uint4*>(&Qs[r * PST + off]) =
            *reinterpret_cast<const uint4*>(&Q[(size_t)(b * L_SEQ + q0 + r) * D_MODEL + h * D_K + off]);
    }

    // swizzled staging: LDS chunk p holds (row=p>>3, c8=((p&7)-row)&7); 512 chunks
    // per sub-tile, one per thread per sub-tile for each of Ks and Vs.
    const int p0 = tid, sr0 = p0 >> 3, sc0 = (((p0 & 7) - sr0) & 7) * 8;
    const unsigned short* K0 = K + (size_t)(b * L_SEQ + sr0) * D_MODEL + h * D_K + sc0;
    const unsigned short* V0 = Vt + (size_t)(h * D_K + sr0) * ROWS + b * L_SEQ + sc0;

    // fragment read offsets (loop-invariant): row R = t*16+am, chunk c8 = kt*4 + (lane>>4)
    int offF[2][4];
#pragma unroll
    for (int kt = 0; kt < 2; ++kt)
#pragma unroll
        for (int tt = 0; tt < 4; ++tt) {
            const int R = tt * 16 + am;
            offF[kt][tt] = R * 64 + (((kt * 4 + (lane >> 4)) + R) & 7) * 8;
        }

    __syncthreads();

    shortx8 aQ[2];
    aQ[0] = *reinterpret_cast<const shortx8*>(&Qs[(wave * 16 + am) * PST + aq]);
    aQ[1] = *reinterpret_cast<const shortx8*>(&Qs[(wave * 16 + am) * PST + 32 + aq]);

    floatx4 oacc[4] = {};
    float lsum = 0.0f;

    for (int j0 = 0; j0 < L_SEQ; j0 += 128) {
        __syncthreads();
        glds16(K0 + (size_t)j0 * D_MODEL,        &Ks[0][p0 * 8]);
        glds16(K0 + (size_t)(j0 + 64) * D_MODEL, &Ks[1][p0 * 8]);
        glds16(V0 + j0,      &Vs[0][p0 * 8]);
        glds16(V0 + j0 + 64, &Vs[1][p0 * 8]);
        if (tid < 128) mkb[tid] = (unsigned char)(mask[b * L_SEQ + j0 + tid] != 0);
        __syncthreads();

#pragma unroll
        for (int u = 0; u < 2; ++u) {
            // S^T = K x Q^T: sacc[jt][r] = S[k = u*64 + 16jt + cq + r][q = wave*16 + cn]
            floatx4 sacc[4] = {};
            __builtin_amdgcn_s_setprio(1);
#pragma unroll
            for (int kt = 0; kt < 2; ++kt)
#pragma unroll
                for (int jt = 0; jt < 4; ++jt) {
                    shortx8 bK = *reinterpret_cast<const shortx8*>(&Ks[u][offF[kt][jt]]);
                    sacc[jt] = __builtin_amdgcn_mfma_f32_16x16x32_bf16(bK, aQ[kt], sacc[jt], 0, 0, 0);
                }
            __builtin_amdgcn_s_setprio(0);
            // P = exp2(S^T) masked; pack k-pairs via v_cvt_pk_bf16_f32 -> ds_write_b64
            // into Ps[q][k] (same layout the PV reads expect).
#pragma unroll
            for (int jt = 0; jt < 4; ++jt) {
                uchar4 mb = *reinterpret_cast<const uchar4*>(&mkb[u * 64 + jt * 16 + cq]);
                float pv0 = mb.x ? __builtin_amdgcn_exp2f(sacc[jt][0]) : 0.0f;
                float pv1 = mb.y ? __builtin_amdgcn_exp2f(sacc[jt][1]) : 0.0f;
                float pv2 = mb.z ? __builtin_amdgcn_exp2f(sacc[jt][2]) : 0.0f;
                float pv3 = mb.w ? __builtin_amdgcn_exp2f(sacc[jt][3]) : 0.0f;
                lsum += (pv0 + pv1) + (pv2 + pv3);
                unsigned int pk0, pk1;
                asm("v_cvt_pk_bf16_f32 %0, %1, %2" : "=v"(pk0) : "v"(pv0), "v"(pv1));
                asm("v_cvt_pk_bf16_f32 %0, %1, %2" : "=v"(pk1) : "v"(pv2), "v"(pv3));
                uint2 w; w.x = pk0; w.y = pk1;
                *reinterpret_cast<uint2*>(&Ps[(wave * 16 + cn) * PST + jt * 16 + cq]) = w;
            }
            // O += P x V (wave-private Ps rows; DS in-order within wave -> safe reuse)
            __builtin_amdgcn_s_setprio(1);
#pragma unroll
            for (int kt = 0; kt < 2; ++kt) {
                shortx8 aP = *reinterpret_cast<const shortx8*>(&Ps[(wave * 16 + am) * PST + kt * 32 + aq]);
#pragma unroll
                for (int dt = 0; dt < 4; ++dt) {
                    shortx8 bV = *reinterpret_cast<const shortx8*>(&Vs[u][offF[kt][dt]]);
                    oacc[dt] = __builtin_amdgcn_mfma_f32_16x16x32_bf16(aP, bV, oacc[dt], 0, 0, 0);
                }
            }
            __builtin_amdgcn_s_setprio(0);
        }
    }

    // lsum: thread holds partial for q = wave*16+cn over its k; reduce across the
    // 4 lanes sharing cn (bits 4,5), then redistribute to the oacc layout (q=cq+r).
    float lt = lsum;
    lt += __shfl_xor(lt, 16);
    lt += __shfl_xor(lt, 32);
    float linv[4];
#pragma unroll
    for (int r = 0; r < 4; ++r)
        linv[r] = 1.0f / __shfl(lt, cq + r);

#pragma unroll
    for (int dt = 0; dt < 4; ++dt)
#pragma unroll
        for (int r = 0; r < 4; ++r) {
            att[(size_t)(b * L_SEQ + q0 + wave * 16 + cq + r) * D_MODEL + h * D_K + dt * 16 + cn] =
                f2bf(oacc[dt][r] * linv[r]);
        }
}

extern "C" void kernel_launch(void* const* d_in, const int* in_sizes, int n_in,
                              void* d_out, int out_size, void* d_ws, size_t ws_size,
                              hipStream_t stream) {
    const float* x     = (const float*)d_in[0];
    const int*   mask  = (const int*)d_in[1];
    const float* ln1_g = (const float*)d_in[2];
    const float* ln1_b = (const float*)d_in[3];
    const float* Wq    = (const float*)d_in[4];
    const float* bq    = (const float*)d_in[5];
    const float* Wk    = (const float*)d_in[6];
    const float* bk    = (const float*)d_in[7];
    const float* Wv    = (const float*)d_in[8];
    const float* bv    = (const float*)d_in[9];
    const float* Wo    = (const float*)d_in[10];
    const float* bo    = (const float*)d_in[11];
    const float* ln2_g = (const float*)d_in[12];
    const float* ln2_b = (const float*)d_in[13];
    const float* W1    = (const float*)d_in[14];
    const float* b1    = (const float*)d_in[15];
    const float* W2    = (const float*)d_in[16];
    const float* b2    = (const float*)d_in[17];
    float* out = (float*)d_out;

    float* ws = (float*)d_ws;
    const size_t SZ = (size_t)ROWS * D_MODEL;  // 4M elements; fp32 slot = 16 MB

    unsigned short* nx  = (unsigned short*)(ws + 0 * SZ);   // 0-8 MB: LN1/LN2 out bf16
    unsigned short* qb  = (unsigned short*)(ws + 1 * SZ);   // 16-24: Q bf16 (pre-scaled)
    unsigned short* kb  = qb + SZ;                          // 24-32: K bf16
    unsigned short* vtb = (unsigned short*)(ws + 2 * SZ);   // 32-40: V^T bf16
    unsigned short* attb = vtb + SZ;                        // 40-48: att bf16
    float* x1  = out;                                       // residual stream in d_out
    unsigned short* nx2 = nx;                               // slot0 reuse
    unsigned short* h = (unsigned short*)(ws + 2 * SZ);     // 32-64: FFN hidden bf16
    unsigned short* parts = (unsigned short*)(ws + 0 * SZ); // 0-16: FFN2 split-K partials

    unsigned short* WqkvT = (unsigned short*)(ws + 4 * SZ); // 64-70: concat [3072][1024]
    unsigned short* WqT = WqkvT;
    unsigned short* WkT = WqkvT + (size_t)D_MODEL * D_MODEL;
    unsigned short* WvT = WkT + (size_t)D_MODEL * D_MODEL;
    unsigned short* WoT = WvT + (size_t)D_MODEL * D_MODEL;  // 70-72
    unsigned short* W1T = (unsigned short*)(ws + 1 * SZ);   // 16-24 (qb/kb dead after attn)
    unsigned short* W2T = W1T + (size_t)D_MODEL * FFN_DIM;  // 24-32

    ln_kernel<<<ROWS, 256, 0, stream>>>(x, ln1_g, ln1_b, nx);

    transpose_cast4<<<dim3(32, 32, 4), 256, 0, stream>>>(Wq, Wk, Wv, Wo, WqT, WkT, WvT, WoT);

    mfma_gemm_qkv<<<dim3(3072 / 128, ROWS / 128), 256, 0, stream>>>(
        nx, WqkvT, bq, bk, bv, qb, kb, vtb);

    attn_mfma<<<dim3(L_SEQ / 128, N_HEAD, B_SZ), 512, 0, stream>>>(qb, kb, vtb, mask, attb);

    transpose_cast<<<dim3(FFN_DIM / 32, D_MODEL / 32), 256, 0, stream>>>(W1, W1T, D_MODEL, FFN_DIM);
    transpose_cast<<<dim3(D_MODEL / 32, FFN_DIM / 32), 256, 0, stream>>>(W2, W2T, FFN_DIM, D_MODEL);

    mfma_gemm<0, 1, 0><<<dim3(D_MODEL / 128, ROWS / 128), 256, 0, stream>>>(
        attb, WoT, bo, x, x1, ROWS, D_MODEL, D_MODEL);

    ln_kernel<<<ROWS, 256, 0, stream>>>(x1, ln2_g, ln2_b, nx2);

    mfma_gemm<1, 0, 1><<<dim3(FFN_DIM / 128, ROWS / 128), 256, 0, stream>>>(
        nx2, W1T, b1, nullptr, h, ROWS, FFN_DIM, D_MODEL);

    mfma_gemm_splitk<<<dim3(D_MODEL / 128, ROWS / 128, 2), 256, 0, stream>>>(
        h, W2T, parts, ROWS, D_MODEL, FFN_DIM / 2);
    combine_kernel<<<(ROWS * D_MODEL) / 1024, 256, 0, stream>>>(
        parts, parts + SZ, b2, x1, out);
}